// Round 5
// baseline (374.597 us; speedup 1.0000x reference)
//
#include <hip/hip_runtime.h>
#include <math.h>

// Problem: B=4, S=4096, H=2048, E=64, K=8; T = 16384 tokens.
#define HDIM 2048
#define TTOK 16384
#define NEXP 64
#define TOPK 8
#define SLEN 4096
#define NBATCH 4

// Output layout (flat, float32):
#define OFF_W    131072
#define OFF_LOSS 262144
#define OFF_LOAD 262145

// ws layout (float offsets): Pacc[4][64] @0, Cacc[4][64] @256, counter @512,
// WF (frag-ordered bf16 W planes) @1024: 2 planes x 32 kt x 4 nt x 2 reg x
// 64 lane x 8 ushort = 262144 ushorts (512 KB).
#define WS_PACC 0
#define WS_CACC 256
#define WS_CNT  512
#define WS_WF   1024
#define WFLO    131072  // ushort offset of lo plane within WF
#define NBLK    1024    // gate_fused grid

using s16x8 = __attribute__((ext_vector_type(8))) short;   // 8 bf16 (4 VGPR)
using f32x4 = __attribute__((ext_vector_type(4))) float;   // MFMA acc

// bf16 round-to-nearest-even of fp32 (finite inputs only)
__device__ __forceinline__ unsigned bfh(float v) {
  unsigned b = __float_as_uint(v);
  return (b + 0x7FFFu + ((b >> 16) & 1u)) >> 16;
}

// split float4 into hi/lo bf16 planes, packed 4x bf16 per uint2
__device__ __forceinline__ void split4(float4 v, uint2* hi, uint2* lo) {
  unsigned h0 = bfh(v.x), h1 = bfh(v.y), h2 = bfh(v.z), h3 = bfh(v.w);
  float r0 = v.x - __uint_as_float(h0 << 16);
  float r1 = v.y - __uint_as_float(h1 << 16);
  float r2 = v.z - __uint_as_float(h2 << 16);
  float r3 = v.w - __uint_as_float(h3 << 16);
  unsigned l0 = bfh(r0), l1 = bfh(r1), l2 = bfh(r2), l3 = bfh(r3);
  *hi = make_uint2(h0 | (h1 << 16), h2 | (h3 << 16));
  *lo = make_uint2(l0 | (l1 << 16), l2 | (l3 << 16));
}

// pack two uint2 (4 bf16 each) into one s16x8 frag, k ascending
__device__ __forceinline__ s16x8 pk8(uint2 a, uint2 b) {
  uint4 u = make_uint4(a.x, a.y, b.x, b.y);
  return *(s16x8*)&u;
}

// ---------------------------------------------------------------------------
// W fp32 [64][2048] -> WF: B-frag-ordered bf16 planes (R4-proven, unchanged).
// WF index (ushort/8): ((plane*32 + kt)*4 + nt)*2 + reg, then lane, then 8 k.
// Lane (fl=lane&15, fg=lane>>4) holds W[nt*16+fl][kt*64 + reg*32 + fg*8 ..+8].
__global__ __launch_bounds__(256) void prep_wf(const float* __restrict__ W,
                                               ushort* __restrict__ WF) {
  const int id = blockIdx.x * 256 + threadIdx.x;  // grid 128 -> 32768
  const int lane = id & 63;
  const int reg = (id >> 6) & 1;
  const int nt = (id >> 7) & 3;
  const int kt = (id >> 9) & 31;
  const int plane = id >> 14;  // 0=hi, 1=lo
  const int e = (nt << 4) + (lane & 15);
  const int k0 = (kt << 6) + (reg << 5) + ((lane >> 4) << 3);
  const float* src = W + (size_t)e * HDIM + k0;
  unsigned w[4];
#pragma unroll
  for (int j = 0; j < 4; ++j) {
    float v0 = src[2 * j], v1 = src[2 * j + 1];
    unsigned h0 = bfh(v0), h1 = bfh(v1);
    if (plane) {
      h0 = bfh(v0 - __uint_as_float(h0 << 16));
      h1 = bfh(v1 - __uint_as_float(h1 << 16));
    }
    w[j] = h0 | (h1 << 16);
  }
  *(uint4*)(WF + ((size_t)id << 3)) = make_uint4(w[0], w[1], w[2], w[3]);
}

// ---------------------------------------------------------------------------
// Fused gate, barrier-free main loop: grid 1024 x 256 thr = 4 waves.
// Block = 16 tokens x 64 experts x full K. Wave kq (0..3): 16 tok x 64 exp
// over k-quarter [512kq, 512kq+512), fully autonomous: A-frags direct from
// global x with in-register fp32->bf16 hi/lo split (each x element loaded
// and converted exactly once chip-wide), B-frags from frag-ordered WF (L2).
// ZERO barriers in the loop -> compiler emits counted vmcnt, deep pipeline;
// 4 waves/SIMD cover load latency (the R0..R4 barrier-drain disease removed).
// K-quarter partials combined in LDS: (p0+p1)+(p2+p3), k ascending within
// quarters (R2-proven KS=4 FP family). 3-term MFMA order identical to R3/R4.
// C/D mapping (m89-verified): col=lane&15 (expert), row=(lane>>4)*4+reg.
__global__ __launch_bounds__(256, 4) void gate_fused(
    const float* __restrict__ x,    // [16384][2048]
    const ushort* __restrict__ WF,  // frag-ordered bf16 planes
    const float* __restrict__ bias, // [64]
    float* __restrict__ out, float* __restrict__ Pacc,
    float* __restrict__ Cacc, int* __restrict__ counter) {
  __shared__ float pac[4][16][65];  // k-quarter partials, 16.6 KB
  __shared__ float le[16 * 65];     // logits [token][expert], padded
  __shared__ float sgm[16 * 65];    // sigmoid(logits), padded
  __shared__ float rinvs[16];
  __shared__ float biasl[64];
  __shared__ unsigned csum[64];
  __shared__ int lastf;

  const int tid = threadIdx.x;
  const int lane = tid & 63;
  const int kq = __builtin_amdgcn_readfirstlane(tid >> 6);  // k-quarter 0..3
  const int tok0 = blockIdx.x << 4;  // 16 tokens/block, 1024 blocks

  if (tid < 64) { csum[tid] = 0u; biasl[tid] = bias[tid]; }

  const int fl = lane & 15, fg = lane >> 4;
  // A source: row tok0+fl, k = kq*512 + st*64 + fg*8 (+0..7 / +32..39)
  const float* xr = x + (size_t)(tok0 + fl) * HDIM + (kq << 9) + (fg << 3);
  // B source: frag-ordered, kt = kq*8 + st
  const ushort* wbase = WF + ((size_t)lane << 3);

  f32x4 acc[4];
#pragma unroll
  for (int n = 0; n < 4; ++n) acc[n] = (f32x4){0.f, 0.f, 0.f, 0.f};

#pragma unroll 2
  for (int st = 0; st < 8; ++st) {
    const int kt = (kq << 3) + st;
    const float* xs = xr + (st << 6);
    float4 v0 = *(const float4*)xs;         // k+0..3
    float4 v1 = *(const float4*)(xs + 4);   // k+4..7
    float4 v2 = *(const float4*)(xs + 32);  // k+32..35
    float4 v3 = *(const float4*)(xs + 36);  // k+36..39
    uint2 h0, l0, h1, l1, h2, l2, h3, l3;
    split4(v0, &h0, &l0); split4(v1, &h1, &l1);
    split4(v2, &h2, &l2); split4(v3, &h3, &l3);
    s16x8 ah0 = pk8(h0, h1), al0 = pk8(l0, l1);
    s16x8 ah1 = pk8(h2, h3), al1 = pk8(l2, l3);
    const ushort* wk = wbase + ((size_t)kt << 12);
#pragma unroll
    for (int nt = 0; nt < 4; ++nt) {
      const ushort* wp = wk + (nt << 10);
      s16x8 bh0 = *(const s16x8*)wp;
      s16x8 bh1 = *(const s16x8*)(wp + 512);
      s16x8 bl0 = *(const s16x8*)(wp + WFLO);
      s16x8 bl1 = *(const s16x8*)(wp + WFLO + 512);
      // identical term order to R3/R4: (al*bh, ah*bl, ah*bh) per K-half
      acc[nt] = __builtin_amdgcn_mfma_f32_16x16x32_bf16(al0, bh0, acc[nt], 0, 0, 0);
      acc[nt] = __builtin_amdgcn_mfma_f32_16x16x32_bf16(ah0, bl0, acc[nt], 0, 0, 0);
      acc[nt] = __builtin_amdgcn_mfma_f32_16x16x32_bf16(ah0, bh0, acc[nt], 0, 0, 0);
      acc[nt] = __builtin_amdgcn_mfma_f32_16x16x32_bf16(al1, bh1, acc[nt], 0, 0, 0);
      acc[nt] = __builtin_amdgcn_mfma_f32_16x16x32_bf16(ah1, bl1, acc[nt], 0, 0, 0);
      acc[nt] = __builtin_amdgcn_mfma_f32_16x16x32_bf16(ah1, bh1, acc[nt], 0, 0, 0);
    }
  }

  // ---- publish k-quarter partials (C/D: row=fg*4+r, col=nt*16+fl) ----
#pragma unroll
  for (int nt = 0; nt < 4; ++nt) {
#pragma unroll
    for (int r = 0; r < 4; ++r)
      pac[kq][(fg << 2) + r][(nt << 4) + fl] = acc[nt][r];
  }
  __syncthreads();

  // ---- combine quarters (deterministic pairwise) + sigmoid ----
  {
    const int col = tid & 63;
    const int r4 = tid >> 6;
#pragma unroll
    for (int r = 0; r < 4; ++r) {
      const int row = (r4 << 2) + r;
      float s = (pac[0][row][col] + pac[1][row][col]) +
                (pac[2][row][col] + pac[3][row][col]);
      le[row * 65 + col] = s;
      sgm[row * 65 + col] = 1.f / (1.f + expf(-s));
    }
  }
  __syncthreads();

  const int b = (int)(blockIdx.x >> 8);  // batch (256 blocks/batch)

  if (kq == 0) {
    // per-token top-8 (lane = token, 16 active), proven scan structure
    if (lane < 16) {
      const int t = lane;
      float bl[64];
#pragma unroll
      for (int e = 0; e < NEXP; ++e) bl[e] = le[t * 65 + e] + biasl[e];

      unsigned long long chosen = 0ull;
      int i8[TOPK];
      float w8[TOPK];
      float wsum = 0.f;
#pragma unroll
      for (int j = 0; j < TOPK; ++j) {
        float best = -1e30f;
        int bi = 0;
#pragma unroll
        for (int e = 0; e < NEXP; ++e) {
          bool ok = (((chosen >> e) & 1ull) == 0ull) && (bl[e] > best);
          if (ok) { best = bl[e]; bi = e; }
        }
        chosen |= (1ull << bi);
        float sc = sgm[t * 65 + bi];
        i8[j] = bi;
        w8[j] = sc;
        wsum += sc;
      }
      const float inv = 1.f / (wsum + 1e-10f);
      const int tt = tok0 + t;
      float4 o;
      o.x = (float)i8[0]; o.y = (float)i8[1]; o.z = (float)i8[2]; o.w = (float)i8[3];
      *(float4*)(out + (size_t)tt * TOPK) = o;
      o.x = (float)i8[4]; o.y = (float)i8[5]; o.z = (float)i8[6]; o.w = (float)i8[7];
      *(float4*)(out + (size_t)tt * TOPK + 4) = o;
      o.x = w8[0] * inv; o.y = w8[1] * inv; o.z = w8[2] * inv; o.w = w8[3] * inv;
      *(float4*)(out + OFF_W + (size_t)tt * TOPK) = o;
      o.x = w8[4] * inv; o.y = w8[5] * inv; o.z = w8[6] * inv; o.w = w8[7] * inv;
      *(float4*)(out + OFF_W + (size_t)tt * TOPK + 4) = o;
#pragma unroll
      for (int j = 0; j < TOPK; ++j) atomicAdd(&csum[i8[j]], 1u);
    }
    // wave-lockstep: lanes<16's LDS atomics precede this in program order
    atomicAdd(&Cacc[(b << 6) + lane], (float)csum[lane]);
  } else if (kq == 1) {
    // row sums of sigmoids -> rinv (16 tokens), then per-expert P partial
    if (lane < 16) {
      const int t = lane;
      float ss = 0.f;
      for (int e = 0; e < NEXP; ++e) ss += sgm[t * 65 + e];
      rinvs[t] = 1.f / (ss + 1e-10f);
    }
    // same-wave LDS RAW -> ordered via lgkmcnt
    float p = 0.f;
#pragma unroll
    for (int t2 = 0; t2 < 16; ++t2) p += sgm[t2 * 65 + lane] * rinvs[t2];
    atomicAdd(&Pacc[(b << 6) + lane], p);
  }

  __syncthreads();
  __threadfence();
  if (tid == 0) {
    int old = __hip_atomic_fetch_add(counter, 1, __ATOMIC_ACQ_REL,
                                     __HIP_MEMORY_SCOPE_AGENT);
    lastf = (old == NBLK - 1) ? 1 : 0;
  }
  __syncthreads();

  if (lastf && tid < 64) {
    const int e = tid;
    float load = 0.f, partl = 0.f;
#pragma unroll
    for (int bb = 0; bb < NBATCH; ++bb) {
      float c = __hip_atomic_load(&Cacc[(bb << 6) + e], __ATOMIC_RELAXED,
                                  __HIP_MEMORY_SCOPE_AGENT);
      float p = __hip_atomic_load(&Pacc[(bb << 6) + e], __ATOMIC_RELAXED,
                                  __HIP_MEMORY_SCOPE_AGENT);
      load += c;
      partl += (c * (1.f / (TOPK * (float)SLEN))) * (p * (1.f / (float)SLEN));
    }
    out[OFF_LOAD + e] = load;
#pragma unroll
    for (int off = 32; off; off >>= 1) partl += __shfl_down(partl, off);
    if (e == 0) out[OFF_LOSS] = 0.01f * partl * (1.f / (float)NBATCH);
  }
}

// ---------------------------------------------------------------------------
extern "C" void kernel_launch(void* const* d_in, const int* in_sizes, int n_in,
                              void* d_out, int out_size, void* d_ws, size_t ws_size,
                              hipStream_t stream) {
  const float* x = (const float*)d_in[0];     // [4,4096,2048]
  const float* W = (const float*)d_in[1];     // [64,2048]
  const float* bias = (const float*)d_in[2];  // [64]
  float* out = (float*)d_out;

  float* ws = (float*)d_ws;
  float* Pacc = ws + WS_PACC;
  float* Cacc = ws + WS_CACC;
  int* counter = (int*)(ws + WS_CNT);
  ushort* WF = (ushort*)(ws + WS_WF);

  hipMemsetAsync(ws, 0, 1024 * sizeof(float), stream);
  prep_wf<<<128, 256, 0, stream>>>(W, WF);
  gate_fused<<<NBLK, 256, 0, stream>>>(x, WF, bias, out, Pacc, Cacc, counter);
}

// Round 6
// 345.991 us; speedup vs baseline: 1.0827x; 1.0827x over previous
//
#include <hip/hip_runtime.h>
#include <math.h>

// Problem: B=4, S=4096, H=2048, E=64, K=8; T = 16384 tokens.
#define HDIM 2048
#define TTOK 16384
#define NEXP 64
#define TOPK 8
#define SLEN 4096
#define NBATCH 4
#define PARTSZ (NEXP * TTOK)  // floats per k-split partial (4 MB)

// Output layout (flat, float32):
#define OFF_W    131072
#define OFF_LOSS 262144
#define OFF_LOAD 262145

// ws layout (float offsets): Pacc[4][64] @0, Cacc[4][64] @256, counter @512,
// Wt [2048][64] @1024, partials @WS_PART (KS x [64][16384]).
#define WS_PACC 0
#define WS_CACC 256
#define WS_CNT  512
#define WS_WT   1024
#define WS_PART (1024 + HDIM * NEXP)
#define EPI_NBLK 1024  // epilogue grid (16 tokens/block)

// ---------------------------------------------------------------------------
// LDS-tiled transpose W [64][2048] -> Wt [2048][64] (R2-proven).
// Block 0 additionally zeroes Pacc/Cacc/counter (replaces the memset
// dispatch; stream-ordered before gemm/epilogue).
__global__ __launch_bounds__(256) void transpose_w(const float* __restrict__ W,
                                                   float* __restrict__ Wt,
                                                   float* __restrict__ wsz) {
  __shared__ float tile[64][65];
  const int tid = threadIdx.x;
  const int k0 = blockIdx.x * 64;
  if (blockIdx.x == 0) {
    wsz[tid] = 0.f;          // Pacc
    wsz[tid + 256] = 0.f;    // Cacc
    if (tid == 0) wsz[512] = 0.f;  // counter (int 0 == float 0.0 bits)
  }
  {
    const int kc = (tid & 15) << 2;
    const int er = tid >> 4;
#pragma unroll
    for (int i = 0; i < 4; ++i) {
      int e = er + i * 16;
      float4 v = *(const float4*)(W + (size_t)e * HDIM + k0 + kc);
      tile[e][kc + 0] = v.x; tile[e][kc + 1] = v.y;
      tile[e][kc + 2] = v.z; tile[e][kc + 3] = v.w;
    }
  }
  __syncthreads();
  {
    const int e4 = (tid & 15) << 2;
    const int kr = tid >> 4;
#pragma unroll
    for (int i = 0; i < 4; ++i) {
      int k = kr + i * 16;
      float4 v;
      v.x = tile[e4 + 0][k]; v.y = tile[e4 + 1][k];
      v.z = tile[e4 + 2][k]; v.w = tile[e4 + 3][k];
      *(float4*)(Wt + (size_t)(k0 + k) * NEXP + e4) = v;
    }
  }
}

// ---------------------------------------------------------------------------
// GEMM (R0-proven 87 us, VERBATIM): grid KS*128; block 512 = 8 waves =
// 2 token-halves x 4 expert-groups. Block covers 128 tokens x 64 experts x
// (2048/KS) k. Lane = token. x tile [128 tok][32 k] in LDS, slot =
// granule ^ (row&7). One ds_read_b128 feeds 64 FMAs; one s_load_dwordx16
// feeds 16. Per-acc k strictly ascending within split.
template <int KS>
__global__ __launch_bounds__(512, 8) void gate_gemm(
    const float* __restrict__ x,    // [16384][2048]
    const float* __restrict__ Wt,   // [2048][64]
    float* __restrict__ part) {     // KS x [64][16384]
  constexpr int KR = HDIM / KS;
  constexpr int NT = KR / 32;
  __shared__ float xs[2][128 * 32];  // 32 KB double buffer

  const int tid = threadIdx.x;
  const int lane = tid & 63;
  const int wv = __builtin_amdgcn_readfirstlane(tid >> 6);  // 0..7
  const int eg = wv & 3;        // expert group: [16eg, 16eg+16)
  const int th = wv >> 2;       // token half
  const int bid = blockIdx.x;
  const int kh = bid & (KS - 1);
  const int tg = bid >> (KS == 8 ? 3 : 2);
  const int tok0 = tg << 7;     // 128 tokens/block
  const int kb = kh * KR;

  float acc[16];
#pragma unroll
  for (int j = 0; j < 16; ++j) acc[j] = 0.f;

  // staging: thread -> rows r0 and r0+64, granule sg (16B), swizzled slot
  const int r0 = tid >> 3;      // 0..63
  const int sg = tid & 7;       // 0..7
  const int sslot = (sg ^ (r0 & 7)) << 2;
  const float* xp0 = x + (size_t)(tok0 + r0) * HDIM + kb + (sg << 2);
  const float* xp1 = xp0 + (size_t)64 * HDIM;
  float4 a0 = *(const float4*)xp0;
  float4 a1 = *(const float4*)xp1;

  const int myrow = (th << 6) + lane;
  const int rbase = myrow << 5;
  const int rs = lane & 7;      // == myrow & 7

  for (int kt = 0; kt < NT; ++kt) {
    float* xb = &xs[kt & 1][0];
    *(float4*)&xb[(r0 << 5) + sslot] = a0;
    *(float4*)&xb[((r0 + 64) << 5) + sslot] = a1;
    __syncthreads();  // single barrier/tile (R2-proven dbuf)
    if (kt + 1 < NT) {
      a0 = *(const float4*)(xp0 + ((kt + 1) << 5));
      a1 = *(const float4*)(xp1 + ((kt + 1) << 5));
    }
    const float* wkb = Wt + ((size_t)(kb + (kt << 5)) << 6) + (eg << 4);
#pragma unroll
    for (int c = 0; c < 8; ++c) {
      // slot (c^rs) of own row holds logical granule c -> k ascending
      float4 xv = *(const float4*)&xb[rbase + ((c ^ rs) << 2)];
      const float xf[4] = {xv.x, xv.y, xv.z, xv.w};
#pragma unroll
      for (int q = 0; q < 4; ++q) {
        const float* wr = wkb + (((c << 2) + q) << 6);  // uniform -> s_load_x16
#pragma unroll
        for (int j = 0; j < 16; ++j) acc[j] = fmaf(xf[q], wr[j], acc[j]);
      }
    }
  }

  // partial store [kh][e][tok], 64-lane coalesced per expert row
  float* dst = part + (size_t)kh * PARTSZ + ((size_t)(eg << 4)) * TTOK + tok0 +
               (th << 6) + lane;
#pragma unroll
  for (int j = 0; j < 16; ++j) dst[(size_t)j * TTOK] = acc[j];
}

// ---------------------------------------------------------------------------
// Epilogue v2: grid 1024 x 256 thr; block = 16 tok x 64 e. Same math/FP
// order as the R0-proven 256x128 version, but 4x grid and 8-deep per-lane
// partial loads (all KS loads in flight before summing) -> latency-covered.
template <int KS>
__global__ __launch_bounds__(256) void gate_epilogue(
    const float* __restrict__ part, const float* __restrict__ bias,
    float* __restrict__ out, float* __restrict__ Pacc,
    float* __restrict__ Cacc, int* __restrict__ counter) {
  __shared__ float le[64][17];   // [expert][token(16)+pad]
  __shared__ float rinv_sh[16];
  __shared__ unsigned csum[64];
  __shared__ int lastf;

  const int tid = threadIdx.x;
  const int t0 = blockIdx.x << 4;  // 16 tokens/block

  if (tid < 64) csum[tid] = 0u;

  // phase 1: pairwise-tree sum of KS partials; thread = (e, 4 tokens)
  {
    const int e = tid >> 2;
    const int tq = (tid & 3) << 2;
    const float* p = part + (size_t)e * TTOK + t0 + tq;
    float4 v[KS];
#pragma unroll
    for (int s = 0; s < KS; ++s) v[s] = *(const float4*)(p + (size_t)s * PARTSZ);
    float4 r;
    if (KS == 8) {
      r.x = ((v[0].x + v[1].x) + (v[2].x + v[3].x)) + ((v[4].x + v[5].x) + (v[6].x + v[7].x));
      r.y = ((v[0].y + v[1].y) + (v[2].y + v[3].y)) + ((v[4].y + v[5].y) + (v[6].y + v[7].y));
      r.z = ((v[0].z + v[1].z) + (v[2].z + v[3].z)) + ((v[4].z + v[5].z) + (v[6].z + v[7].z));
      r.w = ((v[0].w + v[1].w) + (v[2].w + v[3].w)) + ((v[4].w + v[5].w) + (v[6].w + v[7].w));
    } else {
      r.x = (v[0].x + v[1].x) + (v[2].x + v[3].x);
      r.y = (v[0].y + v[1].y) + (v[2].y + v[3].y);
      r.z = (v[0].z + v[1].z) + (v[2].z + v[3].z);
      r.w = (v[0].w + v[1].w) + (v[2].w + v[3].w);
    }
    le[e][tq + 0] = r.x; le[e][tq + 1] = r.y;
    le[e][tq + 2] = r.z; le[e][tq + 3] = r.w;
  }
  __syncthreads();

  // phase 2: per-token top-8 (thread = token, 16 active)
  if (tid < 16) {
    const int t = tid;
    float bl[64];
    float ssum = 0.f;
#pragma unroll
    for (int e = 0; e < NEXP; ++e) {
      float l = le[e][t];
      ssum += 1.f / (1.f + expf(-l));
      bl[e] = l + bias[e];
    }
    rinv_sh[t] = 1.f / (ssum + 1e-10f);

    unsigned long long chosen = 0ull;
    int i8[TOPK];
    float w8[TOPK];
    float wsum = 0.f;
#pragma unroll
    for (int j = 0; j < TOPK; ++j) {
      float best = -1e30f;
      int bi = 0;
      float braw = 0.f;
#pragma unroll
      for (int e = 0; e < NEXP; ++e) {
        bool ok = (((chosen >> e) & 1ull) == 0ull) && (bl[e] > best);
        if (ok) { best = bl[e]; bi = e; braw = bl[e] - bias[e]; }
      }
      chosen |= (1ull << bi);
      float sc = 1.f / (1.f + expf(-braw));
      i8[j] = bi;
      w8[j] = sc;
      wsum += sc;
    }
    const float inv = 1.f / (wsum + 1e-10f);
    const int t1 = t0 + t;
    float4 o;
    o.x = (float)i8[0]; o.y = (float)i8[1]; o.z = (float)i8[2]; o.w = (float)i8[3];
    *(float4*)(out + (size_t)t1 * TOPK) = o;
    o.x = (float)i8[4]; o.y = (float)i8[5]; o.z = (float)i8[6]; o.w = (float)i8[7];
    *(float4*)(out + (size_t)t1 * TOPK + 4) = o;
    o.x = w8[0] * inv; o.y = w8[1] * inv; o.z = w8[2] * inv; o.w = w8[3] * inv;
    *(float4*)(out + OFF_W + (size_t)t1 * TOPK) = o;
    o.x = w8[4] * inv; o.y = w8[5] * inv; o.z = w8[6] * inv; o.w = w8[7] * inv;
    *(float4*)(out + OFF_W + (size_t)t1 * TOPK + 4) = o;
#pragma unroll
    for (int j = 0; j < TOPK; ++j) atomicAdd(&csum[i8[j]], 1u);
  }
  __syncthreads();

  // phase 3: thread = expert; row sums of normalized scores over 16 tokens
  const int b = blockIdx.x >> 8;  // 256 blocks per batch
  if (tid < 64) {
    float p = 0.f;
#pragma unroll
    for (int tt = 0; tt < 16; ++tt) {
      float sc = 1.f / (1.f + expf(-le[tid][tt]));
      p += sc * rinv_sh[tt];
    }
    atomicAdd(&Pacc[(b << 6) + tid], p);
    atomicAdd(&Cacc[(b << 6) + tid], (float)csum[tid]);
  }
  __syncthreads();
  __threadfence();
  if (tid == 0) {
    int old = __hip_atomic_fetch_add(counter, 1, __ATOMIC_ACQ_REL,
                                     __HIP_MEMORY_SCOPE_AGENT);
    lastf = (old == EPI_NBLK - 1) ? 1 : 0;
  }
  __syncthreads();

  if (lastf && tid < 64) {
    const int e = tid;
    float load = 0.f, partl = 0.f;
#pragma unroll
    for (int bb = 0; bb < NBATCH; ++bb) {
      float c = __hip_atomic_load(&Cacc[(bb << 6) + e], __ATOMIC_RELAXED,
                                  __HIP_MEMORY_SCOPE_AGENT);
      float p = __hip_atomic_load(&Pacc[(bb << 6) + e], __ATOMIC_RELAXED,
                                  __HIP_MEMORY_SCOPE_AGENT);
      load += c;
      partl += (c * (1.f / (TOPK * (float)SLEN))) * (p * (1.f / (float)SLEN));
    }
    out[OFF_LOAD + e] = load;
#pragma unroll
    for (int off = 32; off; off >>= 1) partl += __shfl_down(partl, off);
    if (e == 0) out[OFF_LOSS] = 0.01f * partl * (1.f / (float)NBATCH);
  }
}

// ---------------------------------------------------------------------------
extern "C" void kernel_launch(void* const* d_in, const int* in_sizes, int n_in,
                              void* d_out, int out_size, void* d_ws, size_t ws_size,
                              hipStream_t stream) {
  const float* x = (const float*)d_in[0];     // [4,4096,2048]
  const float* W = (const float*)d_in[1];     // [64,2048]
  const float* bias = (const float*)d_in[2];  // [64]
  float* out = (float*)d_out;

  float* ws = (float*)d_ws;
  float* Pacc = ws + WS_PACC;
  float* Cacc = ws + WS_CACC;
  int* counter = (int*)(ws + WS_CNT);
  float* Wt = ws + WS_WT;
  float* part = ws + WS_PART;

  transpose_w<<<32, 256, 0, stream>>>(W, Wt, ws);

  const size_t need8 = ((size_t)WS_PART + 8 * (size_t)PARTSZ) * sizeof(float);
  if (ws_size >= need8) {
    gate_gemm<8><<<1024, 512, 0, stream>>>(x, Wt, part);
    gate_epilogue<8><<<EPI_NBLK, 256, 0, stream>>>(part, bias, out, Pacc, Cacc, counter);
  } else {
    gate_gemm<4><<<512, 512, 0, stream>>>(x, Wt, part);
    gate_epilogue<4><<<EPI_NBLK, 256, 0, stream>>>(part, bias, out, Pacc, Cacc, counter);
  }
}

// Round 8
// 263.014 us; speedup vs baseline: 1.4242x; 1.3155x over previous
//
#include <hip/hip_runtime.h>
#include <math.h>

// Problem: B=4, S=4096, H=2048, E=64, K=8; T = 16384 tokens.
#define HDIM 2048
#define TTOK 16384
#define NEXP 64
#define TOPK 8
#define SLEN 4096
#define NBATCH 4
#define PARTSZ (NEXP * TTOK)  // floats per k-split partial (4 MB)

// Output layout (flat, float32):
#define OFF_W    131072
#define OFF_LOSS 262144
#define OFF_LOAD 262145

// ws layout (float offsets):
//   PaccPad: 256 entries (b,e), PADDED one 128B line each -> 8192 floats @0
//   CaccPad: same @8192
//   Wt [2048][64] @16384
//   partials @WS_PART (KS x [64][16384])
// Padding spreads the epilogue's atomic RMWs over 256 cache lines instead
// of 16 (R6's 118us epilogue was same-line atomic serialization).
#define WS_PACC 0
#define WS_CACC 8192
#define WS_WT   16384
#define WS_PART (16384 + HDIM * NEXP)
#define EPI_NBLK 512  // epilogue grid (32 tokens/block)

// ---------------------------------------------------------------------------
// LDS-tiled transpose W [64][2048] -> Wt [2048][64] (R2-proven).
// Block 0 additionally zeroes the padded accumulators (16384 floats).
__global__ __launch_bounds__(256) void transpose_w(const float* __restrict__ W,
                                                   float* __restrict__ Wt,
                                                   float* __restrict__ wsz) {
  __shared__ float tile[64][65];
  const int tid = threadIdx.x;
  const int k0 = blockIdx.x * 64;
  if (blockIdx.x == 0) {
    const float4 z = {0.f, 0.f, 0.f, 0.f};
    float4* wz4 = (float4*)wsz;
#pragma unroll
    for (int i = 0; i < 16; ++i) wz4[tid + (i << 8)] = z;  // 16384 floats
  }
  {
    const int kc = (tid & 15) << 2;
    const int er = tid >> 4;
#pragma unroll
    for (int i = 0; i < 4; ++i) {
      int e = er + i * 16;
      float4 v = *(const float4*)(W + (size_t)e * HDIM + k0 + kc);
      tile[e][kc + 0] = v.x; tile[e][kc + 1] = v.y;
      tile[e][kc + 2] = v.z; tile[e][kc + 3] = v.w;
    }
  }
  __syncthreads();
  {
    const int e4 = (tid & 15) << 2;
    const int kr = tid >> 4;
#pragma unroll
    for (int i = 0; i < 4; ++i) {
      int k = kr + i * 16;
      float4 v;
      v.x = tile[e4 + 0][k]; v.y = tile[e4 + 1][k];
      v.z = tile[e4 + 2][k]; v.w = tile[e4 + 3][k];
      *(float4*)(Wt + (size_t)(k0 + k) * NEXP + e4) = v;
    }
  }
}

// ---------------------------------------------------------------------------
// GEMM (R0-proven 87 us, VERBATIM): grid KS*128; block 512 = 8 waves =
// 2 token-halves x 4 expert-groups. Block covers 128 tokens x 64 experts x
// (2048/KS) k. Lane = token. x tile [128 tok][32 k] in LDS, slot =
// granule ^ (row&7). One ds_read_b128 feeds 64 FMAs; one s_load_dwordx16
// feeds 16. Per-acc k strictly ascending within split.
template <int KS>
__global__ __launch_bounds__(512, 8) void gate_gemm(
    const float* __restrict__ x,    // [16384][2048]
    const float* __restrict__ Wt,   // [2048][64]
    float* __restrict__ part) {     // KS x [64][16384]
  constexpr int KR = HDIM / KS;
  constexpr int NT = KR / 32;
  __shared__ float xs[2][128 * 32];  // 32 KB double buffer

  const int tid = threadIdx.x;
  const int lane = tid & 63;
  const int wv = __builtin_amdgcn_readfirstlane(tid >> 6);  // 0..7
  const int eg = wv & 3;        // expert group: [16eg, 16eg+16)
  const int th = wv >> 2;       // token half
  const int bid = blockIdx.x;
  const int kh = bid & (KS - 1);
  const int tg = bid >> (KS == 8 ? 3 : 2);
  const int tok0 = tg << 7;     // 128 tokens/block
  const int kb = kh * KR;

  float acc[16];
#pragma unroll
  for (int j = 0; j < 16; ++j) acc[j] = 0.f;

  // staging: thread -> rows r0 and r0+64, granule sg (16B), swizzled slot
  const int r0 = tid >> 3;      // 0..63
  const int sg = tid & 7;       // 0..7
  const int sslot = (sg ^ (r0 & 7)) << 2;
  const float* xp0 = x + (size_t)(tok0 + r0) * HDIM + kb + (sg << 2);
  const float* xp1 = xp0 + (size_t)64 * HDIM;
  float4 a0 = *(const float4*)xp0;
  float4 a1 = *(const float4*)xp1;

  const int myrow = (th << 6) + lane;
  const int rbase = myrow << 5;
  const int rs = lane & 7;      // == myrow & 7

  for (int kt = 0; kt < NT; ++kt) {
    float* xb = &xs[kt & 1][0];
    *(float4*)&xb[(r0 << 5) + sslot] = a0;
    *(float4*)&xb[((r0 + 64) << 5) + sslot] = a1;
    __syncthreads();  // single barrier/tile (R2-proven dbuf)
    if (kt + 1 < NT) {
      a0 = *(const float4*)(xp0 + ((kt + 1) << 5));
      a1 = *(const float4*)(xp1 + ((kt + 1) << 5));
    }
    const float* wkb = Wt + ((size_t)(kb + (kt << 5)) << 6) + (eg << 4);
#pragma unroll
    for (int c = 0; c < 8; ++c) {
      // slot (c^rs) of own row holds logical granule c -> k ascending
      float4 xv = *(const float4*)&xb[rbase + ((c ^ rs) << 2)];
      const float xf[4] = {xv.x, xv.y, xv.z, xv.w};
#pragma unroll
      for (int q = 0; q < 4; ++q) {
        const float* wr = wkb + (((c << 2) + q) << 6);  // uniform -> s_load_x16
#pragma unroll
        for (int j = 0; j < 16; ++j) acc[j] = fmaf(xf[q], wr[j], acc[j]);
      }
    }
  }

  // partial store [kh][e][tok], 64-lane coalesced per expert row
  float* dst = part + (size_t)kh * PARTSZ + ((size_t)(eg << 4)) * TTOK + tok0 +
               (th << 6) + lane;
#pragma unroll
  for (int j = 0; j < 16; ++j) dst[(size_t)j * TTOK] = acc[j];
}

// ---------------------------------------------------------------------------
// Epilogue v3: grid 512 x 256 thr; block = 32 tok x 64 e. Atomic-light:
// NO counter protocol, NO threadfence; Pacc/Cacc atomics hit line-padded
// slots (<=128 RMWs per line, pipelined). One barrier total; phases 2+3
// confined to wave 0 (intra-wave LDS ordering). Same FP order family as
// the passing R0/R6 epilogues.
template <int KS>
__global__ __launch_bounds__(256) void gate_epilogue(
    const float* __restrict__ part, const float* __restrict__ bias,
    float* __restrict__ out, float* __restrict__ Pacc,
    float* __restrict__ Cacc) {
  __shared__ float le[64][33];   // [expert][token(32)+pad]
  __shared__ float rinv_sh[32];
  __shared__ unsigned csum[64];

  const int tid = threadIdx.x;
  const int t0 = blockIdx.x << 5;  // 32 tokens/block

  if (tid < 64) csum[tid] = 0u;

  // phase 1: all 16 per-thread loads in flight, then pairwise-tree sums
  {
    const int e = tid >> 2;
    const int tq = (tid & 3) << 2;
    float4 v[2][KS];
#pragma unroll
    for (int h = 0; h < 2; ++h) {
      const float* p = part + (size_t)e * TTOK + t0 + (h << 4) + tq;
#pragma unroll
      for (int s = 0; s < KS; ++s)
        v[h][s] = *(const float4*)(p + (size_t)s * PARTSZ);
    }
#pragma unroll
    for (int h = 0; h < 2; ++h) {
      float4 r;
      if (KS == 8) {
        r.x = ((v[h][0].x + v[h][1].x) + (v[h][2].x + v[h][3].x)) +
              ((v[h][4].x + v[h][5].x) + (v[h][6].x + v[h][7].x));
        r.y = ((v[h][0].y + v[h][1].y) + (v[h][2].y + v[h][3].y)) +
              ((v[h][4].y + v[h][5].y) + (v[h][6].y + v[h][7].y));
        r.z = ((v[h][0].z + v[h][1].z) + (v[h][2].z + v[h][3].z)) +
              ((v[h][4].z + v[h][5].z) + (v[h][6].z + v[h][7].z));
        r.w = ((v[h][0].w + v[h][1].w) + (v[h][2].w + v[h][3].w)) +
              ((v[h][4].w + v[h][5].w) + (v[h][6].w + v[h][7].w));
      } else {
        r.x = (v[h][0].x + v[h][1].x) + (v[h][2].x + v[h][3].x);
        r.y = (v[h][0].y + v[h][1].y) + (v[h][2].y + v[h][3].y);
        r.z = (v[h][0].z + v[h][1].z) + (v[h][2].z + v[h][3].z);
        r.w = (v[h][0].w + v[h][1].w) + (v[h][2].w + v[h][3].w);
      }
      const int toff = (h << 4) + tq;
      le[e][toff + 0] = r.x; le[e][toff + 1] = r.y;
      le[e][toff + 2] = r.z; le[e][toff + 3] = r.w;
    }
  }
  __syncthreads();

  const int b = (int)(blockIdx.x >> 7);  // batch (128 blocks/batch)

  // phase 2: per-token top-8 (lanes 0..31 of wave 0)
  if (tid < 32) {
    const int t = tid;
    float bl[64];
    float ssum = 0.f;
#pragma unroll
    for (int e = 0; e < NEXP; ++e) {
      float l = le[e][t];
      ssum += 1.f / (1.f + expf(-l));
      bl[e] = l + bias[e];
    }
    rinv_sh[t] = 1.f / (ssum + 1e-10f);

    unsigned long long chosen = 0ull;
    int i8[TOPK];
    float w8[TOPK];
    float wsum = 0.f;
#pragma unroll
    for (int j = 0; j < TOPK; ++j) {
      float best = -1e30f;
      int bi = 0;
      float braw = 0.f;
#pragma unroll
      for (int e = 0; e < NEXP; ++e) {
        bool ok = (((chosen >> e) & 1ull) == 0ull) && (bl[e] > best);
        if (ok) { best = bl[e]; bi = e; braw = bl[e] - bias[e]; }
      }
      chosen |= (1ull << bi);
      float sc = 1.f / (1.f + expf(-braw));
      i8[j] = bi;
      w8[j] = sc;
      wsum += sc;
    }
    const float inv = 1.f / (wsum + 1e-10f);
    const int t1 = t0 + t;
    float4 o;
    o.x = (float)i8[0]; o.y = (float)i8[1]; o.z = (float)i8[2]; o.w = (float)i8[3];
    *(float4*)(out + (size_t)t1 * TOPK) = o;
    o.x = (float)i8[4]; o.y = (float)i8[5]; o.z = (float)i8[6]; o.w = (float)i8[7];
    *(float4*)(out + (size_t)t1 * TOPK + 4) = o;
    o.x = w8[0] * inv; o.y = w8[1] * inv; o.z = w8[2] * inv; o.w = w8[3] * inv;
    *(float4*)(out + OFF_W + (size_t)t1 * TOPK) = o;
    o.x = w8[4] * inv; o.y = w8[5] * inv; o.z = w8[6] * inv; o.w = w8[7] * inv;
    *(float4*)(out + OFF_W + (size_t)t1 * TOPK + 4) = o;
#pragma unroll
    for (int j = 0; j < TOPK; ++j) atomicAdd(&csum[i8[j]], 1u);
  }

  // phase 3: wave 0, thread = expert (csum/rinv_sh written by same wave ->
  // intra-wave LDS program order, no barrier needed)
  if (tid < 64) {
    const int e = tid;
    float p = 0.f;
#pragma unroll
    for (int tt = 0; tt < 32; ++tt) {
      float sc = 1.f / (1.f + expf(-le[e][tt]));
      p += sc * rinv_sh[tt];
    }
    atomicAdd(&Pacc[(size_t)((b << 6) + e) << 5], p);
    atomicAdd(&Cacc[(size_t)((b << 6) + e) << 5], (float)csum[e]);
  }
}

// ---------------------------------------------------------------------------
// Finalize: 1 block, 1 wave. Reads the 256 padded (b,e) accumulators,
// writes expert_load and the aux loss. Replaces the R0/R6 counter protocol
// (512-deep same-address acq-rel RMW chain) with one tiny launch.
__global__ __launch_bounds__(64) void gate_finalize(
    const float* __restrict__ Pacc, const float* __restrict__ Cacc,
    float* __restrict__ out) {
  const int e = threadIdx.x;  // 0..63
  float load = 0.f, partl = 0.f;
#pragma unroll
  for (int bb = 0; bb < NBATCH; ++bb) {
    float c = Cacc[(size_t)((bb << 6) + e) << 5];
    float p = Pacc[(size_t)((bb << 6) + e) << 5];
    load += c;
    partl += (c * (1.f / (TOPK * (float)SLEN))) * (p * (1.f / (float)SLEN));
  }
  out[OFF_LOAD + e] = load;
#pragma unroll
  for (int off = 32; off; off >>= 1) partl += __shfl_down(partl, off);
  if (e == 0) out[OFF_LOSS] = 0.01f * partl * (1.f / (float)NBATCH);
}

// ---------------------------------------------------------------------------
extern "C" void kernel_launch(void* const* d_in, const int* in_sizes, int n_in,
                              void* d_out, int out_size, void* d_ws, size_t ws_size,
                              hipStream_t stream) {
  const float* x = (const float*)d_in[0];     // [4,4096,2048]
  const float* W = (const float*)d_in[1];     // [64,2048]
  const float* bias = (const float*)d_in[2];  // [64]
  float* out = (float*)d_out;

  float* ws = (float*)d_ws;
  float* Pacc = ws + WS_PACC;
  float* Cacc = ws + WS_CACC;
  float* Wt = ws + WS_WT;
  float* part = ws + WS_PART;

  transpose_w<<<32, 256, 0, stream>>>(W, Wt, ws);

  const size_t need8 = ((size_t)WS_PART + 8 * (size_t)PARTSZ) * sizeof(float);
  if (ws_size >= need8) {
    gate_gemm<8><<<1024, 512, 0, stream>>>(x, Wt, part);
    gate_epilogue<8><<<EPI_NBLK, 256, 0, stream>>>(part, bias, out, Pacc, Cacc);
  } else {
    gate_gemm<4><<<512, 512, 0, stream>>>(x, Wt, part);
    gate_epilogue<4><<<EPI_NBLK, 256, 0, stream>>>(part, bias, out, Pacc, Cacc);
  }
  gate_finalize<<<1, 64, 0, stream>>>(Pacc, Cacc, out);
}

// Round 9
// 248.606 us; speedup vs baseline: 1.5068x; 1.0580x over previous
//
#include <hip/hip_runtime.h>
#include <math.h>

// Problem: B=4, S=4096, H=2048, E=64, K=8; T = 16384 tokens.
#define HDIM 2048
#define TTOK 16384
#define NEXP 64
#define TOPK 8
#define SLEN 4096
#define NBATCH 4
#define PARTSZ (NEXP * TTOK)  // floats per k-split partial (4 MB)

// Output layout (flat, float32):
#define OFF_W    131072
#define OFF_LOSS 262144
#define OFF_LOAD 262145

// ws layout (float offsets):
//   PaccPad: 256 entries (b,e), one 128B line each -> 8192 floats @0
//   CaccPad: same @8192
//   Wt [2048][64] @16384
//   partials @WS_PART (KS x [64][16384])
#define WS_PACC 0
#define WS_CACC 8192
#define WS_WT   16384
#define WS_PART (16384 + HDIM * NEXP)
#define EPI_NBLK 256  // epilogue grid (64 tokens/block)

// ---------------------------------------------------------------------------
// LDS-tiled transpose W [64][2048] -> Wt [2048][64] (R2-proven).
// Block 0 additionally zeroes the padded accumulators (16384 floats).
__global__ __launch_bounds__(256) void transpose_w(const float* __restrict__ W,
                                                   float* __restrict__ Wt,
                                                   float* __restrict__ wsz) {
  __shared__ float tile[64][65];
  const int tid = threadIdx.x;
  const int k0 = blockIdx.x * 64;
  if (blockIdx.x == 0) {
    const float4 z = {0.f, 0.f, 0.f, 0.f};
    float4* wz4 = (float4*)wsz;
#pragma unroll
    for (int i = 0; i < 16; ++i) wz4[tid + (i << 8)] = z;  // 16384 floats
  }
  {
    const int kc = (tid & 15) << 2;
    const int er = tid >> 4;
#pragma unroll
    for (int i = 0; i < 4; ++i) {
      int e = er + i * 16;
      float4 v = *(const float4*)(W + (size_t)e * HDIM + k0 + kc);
      tile[e][kc + 0] = v.x; tile[e][kc + 1] = v.y;
      tile[e][kc + 2] = v.z; tile[e][kc + 3] = v.w;
    }
  }
  __syncthreads();
  {
    const int e4 = (tid & 15) << 2;
    const int kr = tid >> 4;
#pragma unroll
    for (int i = 0; i < 4; ++i) {
      int k = kr + i * 16;
      float4 v;
      v.x = tile[e4 + 0][k]; v.y = tile[e4 + 1][k];
      v.z = tile[e4 + 2][k]; v.w = tile[e4 + 3][k];
      *(float4*)(Wt + (size_t)(k0 + k) * NEXP + e4) = v;
    }
  }
}

// ---------------------------------------------------------------------------
// GEMM (R0-proven 87 us, VERBATIM): grid KS*128; block 512 = 8 waves =
// 2 token-halves x 4 expert-groups. Lane = token. x tile [128 tok][32 k] in
// LDS, slot = granule ^ (row&7). Per-acc k strictly ascending within split.
template <int KS>
__global__ __launch_bounds__(512, 8) void gate_gemm(
    const float* __restrict__ x,    // [16384][2048]
    const float* __restrict__ Wt,   // [2048][64]
    float* __restrict__ part) {     // KS x [64][16384]
  constexpr int KR = HDIM / KS;
  constexpr int NT = KR / 32;
  __shared__ float xs[2][128 * 32];  // 32 KB double buffer

  const int tid = threadIdx.x;
  const int lane = tid & 63;
  const int wv = __builtin_amdgcn_readfirstlane(tid >> 6);  // 0..7
  const int eg = wv & 3;        // expert group: [16eg, 16eg+16)
  const int th = wv >> 2;       // token half
  const int bid = blockIdx.x;
  const int kh = bid & (KS - 1);
  const int tg = bid >> (KS == 8 ? 3 : 2);
  const int tok0 = tg << 7;     // 128 tokens/block
  const int kb = kh * KR;

  float acc[16];
#pragma unroll
  for (int j = 0; j < 16; ++j) acc[j] = 0.f;

  const int r0 = tid >> 3;      // 0..63
  const int sg = tid & 7;       // 0..7
  const int sslot = (sg ^ (r0 & 7)) << 2;
  const float* xp0 = x + (size_t)(tok0 + r0) * HDIM + kb + (sg << 2);
  const float* xp1 = xp0 + (size_t)64 * HDIM;
  float4 a0 = *(const float4*)xp0;
  float4 a1 = *(const float4*)xp1;

  const int myrow = (th << 6) + lane;
  const int rbase = myrow << 5;
  const int rs = lane & 7;      // == myrow & 7

  for (int kt = 0; kt < NT; ++kt) {
    float* xb = &xs[kt & 1][0];
    *(float4*)&xb[(r0 << 5) + sslot] = a0;
    *(float4*)&xb[((r0 + 64) << 5) + sslot] = a1;
    __syncthreads();  // single barrier/tile (R2-proven dbuf)
    if (kt + 1 < NT) {
      a0 = *(const float4*)(xp0 + ((kt + 1) << 5));
      a1 = *(const float4*)(xp1 + ((kt + 1) << 5));
    }
    const float* wkb = Wt + ((size_t)(kb + (kt << 5)) << 6) + (eg << 4);
#pragma unroll
    for (int c = 0; c < 8; ++c) {
      float4 xv = *(const float4*)&xb[rbase + ((c ^ rs) << 2)];
      const float xf[4] = {xv.x, xv.y, xv.z, xv.w};
#pragma unroll
      for (int q = 0; q < 4; ++q) {
        const float* wr = wkb + (((c << 2) + q) << 6);  // uniform -> s_load_x16
#pragma unroll
        for (int j = 0; j < 16; ++j) acc[j] = fmaf(xf[q], wr[j], acc[j]);
      }
    }
  }

  float* dst = part + (size_t)kh * PARTSZ + ((size_t)(eg << 4)) * TTOK + tok0 +
               (th << 6) + lane;
#pragma unroll
  for (int j = 0; j < 16; ++j) dst[(size_t)j * TTOK] = acc[j];
}

// ---------------------------------------------------------------------------
// Epilogue v4: ARRAY-FREE wave-parallel top-8. grid 256 x 512 thr.
// Block = 64 tokens. Phase 1: same pairwise k-tree -> le (bit-identical to
// all passing rounds). Phase 2: lane = expert, one register per logit;
// argmax via exact fmax shfl-butterfly + ballot (lowest-index tie-break ==
// serial scan's '>' rule -> bit-identical topk idx/weights). Sigmoid row
// sum + P accumulation fused into the same loop. No bl[64] array (the
// scratch-spill latency chain that made every prior epilogue ~120-130us),
// no phase-3 pass, 2 barriers total.
#define WRED_SUM(v) { v += __shfl_xor(v, 1);  v += __shfl_xor(v, 2);  \
                      v += __shfl_xor(v, 4);  v += __shfl_xor(v, 8);  \
                      v += __shfl_xor(v, 16); v += __shfl_xor(v, 32); }
#define WRED_MAX(v) { v = fmaxf(v, __shfl_xor(v, 1));  v = fmaxf(v, __shfl_xor(v, 2));  \
                      v = fmaxf(v, __shfl_xor(v, 4));  v = fmaxf(v, __shfl_xor(v, 8));  \
                      v = fmaxf(v, __shfl_xor(v, 16)); v = fmaxf(v, __shfl_xor(v, 32)); }
#define PICK(IJ, WJ) {                                                    \
    float m_ = cand; WRED_MAX(m_);                                        \
    unsigned long long mk_ = __ballot(cand == m_);                        \
    int win_ = (int)__ffsll(mk_) - 1;                                     \
    float bw_ = __shfl(bias_r, win_);                                     \
    WJ = 1.f / (1.f + expf(-(m_ - bw_)));                                 \
    wsum += WJ; IJ = win_;                                                \
    if (lane == win_) { cand = -1e30f; cnt += 1.f; } }

template <int KS>
__global__ __launch_bounds__(512) void gate_epilogue(
    const float* __restrict__ part, const float* __restrict__ bias,
    float* __restrict__ out, float* __restrict__ Pacc,
    float* __restrict__ Cacc) {
  __shared__ float le[64 * 65];      // [token][expert], stride 65
  __shared__ float psum_sh[8][64];
  __shared__ float cnt_sh[8][64];

  const int tid = threadIdx.x;
  const int lane = tid & 63;
  const int wv = tid >> 6;           // 0..7
  const int t0 = blockIdx.x << 6;    // 64 tokens/block

  // phase 1: pairwise-tree sum of KS partials (bit-identical le)
  {
    const int e = tid >> 3;           // 0..63
    const int tsub = tid & 7;         // 0..7
#pragma unroll
    for (int w = 0; w < 2; ++w) {
      const int tq = (tsub << 3) + (w << 2);
      const float* p = part + (size_t)e * TTOK + t0 + tq;
      float4 v[KS];
#pragma unroll
      for (int s = 0; s < KS; ++s) v[s] = *(const float4*)(p + (size_t)s * PARTSZ);
      float4 r;
      if (KS == 8) {
        r.x = ((v[0].x + v[1].x) + (v[2].x + v[3].x)) + ((v[4].x + v[5].x) + (v[6].x + v[7].x));
        r.y = ((v[0].y + v[1].y) + (v[2].y + v[3].y)) + ((v[4].y + v[5].y) + (v[6].y + v[7].y));
        r.z = ((v[0].z + v[1].z) + (v[2].z + v[3].z)) + ((v[4].z + v[5].z) + (v[6].z + v[7].z));
        r.w = ((v[0].w + v[1].w) + (v[2].w + v[3].w)) + ((v[4].w + v[5].w) + (v[6].w + v[7].w));
      } else {
        r.x = (v[0].x + v[1].x) + (v[2].x + v[3].x);
        r.y = (v[0].y + v[1].y) + (v[2].y + v[3].y);
        r.z = (v[0].z + v[1].z) + (v[2].z + v[3].z);
        r.w = (v[0].w + v[1].w) + (v[2].w + v[3].w);
      }
      le[(tq + 0) * 65 + e] = r.x; le[(tq + 1) * 65 + e] = r.y;
      le[(tq + 2) * 65 + e] = r.z; le[(tq + 3) * 65 + e] = r.w;
    }
  }
  __syncthreads();

  // phase 2: wave wv handles tokens [8wv, 8wv+8); lane = expert
  const float bias_r = bias[lane];
  float p_acc = 0.f, cnt = 0.f;

  for (int t = (wv << 3); t < (wv << 3) + 8; ++t) {
    float l = le[t * 65 + lane];            // bank (t+e)%32 -> 2-way, free
    float s = 1.f / (1.f + expf(-l));
    float ss = s;
    WRED_SUM(ss);
    p_acc += s * (1.f / (ss + 1e-10f));

    float cand = l + bias_r;
    float wsum = 0.f;
    int i0, i1, i2, i3, i4, i5, i6, i7;
    float w0, w1, w2, w3, w4, w5, w6, w7;
    PICK(i0, w0); PICK(i1, w1); PICK(i2, w2); PICK(i3, w3);
    PICK(i4, w4); PICK(i5, w5); PICK(i6, w6); PICK(i7, w7);

    if (lane == 0) {
      const float inv = 1.f / (wsum + 1e-10f);
      const int t1 = t0 + t;
      float4 o;
      o.x = (float)i0; o.y = (float)i1; o.z = (float)i2; o.w = (float)i3;
      *(float4*)(out + (size_t)t1 * TOPK) = o;
      o.x = (float)i4; o.y = (float)i5; o.z = (float)i6; o.w = (float)i7;
      *(float4*)(out + (size_t)t1 * TOPK + 4) = o;
      o.x = w0 * inv; o.y = w1 * inv; o.z = w2 * inv; o.w = w3 * inv;
      *(float4*)(out + OFF_W + (size_t)t1 * TOPK) = o;
      o.x = w4 * inv; o.y = w5 * inv; o.z = w6 * inv; o.w = w7 * inv;
      *(float4*)(out + OFF_W + (size_t)t1 * TOPK + 4) = o;
    }
  }

  psum_sh[wv][lane] = p_acc;
  cnt_sh[wv][lane] = cnt;
  __syncthreads();

  // combine 8 wave partials (ascending wv) and emit one atomic per (b,e)
  if (tid < 64) {
    const int b = (int)(blockIdx.x >> 6);  // 64 blocks/batch
    float p = 0.f, c = 0.f;
#pragma unroll
    for (int w = 0; w < 8; ++w) { p += psum_sh[w][tid]; c += cnt_sh[w][tid]; }
    atomicAdd(&Pacc[(size_t)((b << 6) + tid) << 5], p);
    atomicAdd(&Cacc[(size_t)((b << 6) + tid) << 5], c);
  }
}

// ---------------------------------------------------------------------------
// Finalize: 1 block, 1 wave (R8-proven).
__global__ __launch_bounds__(64) void gate_finalize(
    const float* __restrict__ Pacc, const float* __restrict__ Cacc,
    float* __restrict__ out) {
  const int e = threadIdx.x;  // 0..63
  float load = 0.f, partl = 0.f;
#pragma unroll
  for (int bb = 0; bb < NBATCH; ++bb) {
    float c = Cacc[(size_t)((bb << 6) + e) << 5];
    float p = Pacc[(size_t)((bb << 6) + e) << 5];
    load += c;
    partl += (c * (1.f / (TOPK * (float)SLEN))) * (p * (1.f / (float)SLEN));
  }
  out[OFF_LOAD + e] = load;
#pragma unroll
  for (int off = 32; off; off >>= 1) partl += __shfl_down(partl, off);
  if (e == 0) out[OFF_LOSS] = 0.01f * partl * (1.f / (float)NBATCH);
}

// ---------------------------------------------------------------------------
extern "C" void kernel_launch(void* const* d_in, const int* in_sizes, int n_in,
                              void* d_out, int out_size, void* d_ws, size_t ws_size,
                              hipStream_t stream) {
  const float* x = (const float*)d_in[0];     // [4,4096,2048]
  const float* W = (const float*)d_in[1];     // [64,2048]
  const float* bias = (const float*)d_in[2];  // [64]
  float* out = (float*)d_out;

  float* ws = (float*)d_ws;
  float* Pacc = ws + WS_PACC;
  float* Cacc = ws + WS_CACC;
  float* Wt = ws + WS_WT;
  float* part = ws + WS_PART;

  transpose_w<<<32, 256, 0, stream>>>(W, Wt, ws);

  const size_t need8 = ((size_t)WS_PART + 8 * (size_t)PARTSZ) * sizeof(float);
  if (ws_size >= need8) {
    gate_gemm<8><<<1024, 512, 0, stream>>>(x, Wt, part);
    gate_epilogue<8><<<EPI_NBLK, 512, 0, stream>>>(part, bias, out, Pacc, Cacc);
  } else {
    gate_gemm<4><<<512, 512, 0, stream>>>(x, Wt, part);
    gate_epilogue<4><<<EPI_NBLK, 512, 0, stream>>>(part, bias, out, Pacc, Cacc);
  }
  gate_finalize<<<1, 64, 0, stream>>>(Pacc, Cacc, out);
}

// Round 11
// 232.918 us; speedup vs baseline: 1.6083x; 1.0674x over previous
//
#include <hip/hip_runtime.h>
#include <math.h>

// Problem: B=4, S=4096, H=2048, E=64, K=8; T = 16384 tokens.
#define HDIM 2048
#define TTOK 16384
#define NEXP 64
#define TOPK 8
#define SLEN 4096
#define NBATCH 4
#define PARTSZ (NEXP * TTOK)  // floats per k-split partial (4 MB)

// Output layout (flat, float32):
#define OFF_W    131072
#define OFF_LOSS 262144
#define OFF_LOAD 262145

// ws layout (float offsets):
//   PaccPad: 256 entries (b,e), one 128B line each -> 8192 floats @0
//   CaccPad: same @8192
//   WF (frag-ordered bf16 W planes) @16384: 262144 ushorts = 131072 floats
//   partials @WS_PART (KS x [16384 tok][64 e])  -- NOTE [tok][e] layout
#define WS_PACC 0
#define WS_CACC 8192
#define WS_WF   16384
#define WS_PART (16384 + 131072)
#define WFLO    131072  // ushort offset of lo plane within WF
#define EPI_NBLK 256    // epilogue grid (64 tokens/block)

using s16x8 = __attribute__((ext_vector_type(8))) short;   // 8 bf16 (4 VGPR)
using f32x4 = __attribute__((ext_vector_type(4))) float;   // MFMA acc

// bf16 round-to-nearest-even of fp32 (finite inputs only)
__device__ __forceinline__ unsigned bfh(float v) {
  unsigned b = __float_as_uint(v);
  return (b + 0x7FFFu + ((b >> 16) & 1u)) >> 16;
}

// 8 floats -> packed hi (uint4) and lo (uint4) bf16 planes, k ascending
__device__ __forceinline__ void split8(const float* f, uint4* hi, uint4* lo) {
  unsigned h[8], l[8];
#pragma unroll
  for (int j = 0; j < 8; ++j) {
    h[j] = bfh(f[j]);
    l[j] = bfh(f[j] - __uint_as_float(h[j] << 16));
  }
  *hi = make_uint4(h[0] | (h[1] << 16), h[2] | (h[3] << 16),
                   h[4] | (h[5] << 16), h[6] | (h[7] << 16));
  *lo = make_uint4(l[0] | (l[1] << 16), l[2] | (l[3] << 16),
                   l[4] | (l[5] << 16), l[6] | (l[7] << 16));
}

// ---------------------------------------------------------------------------
// W fp32 [64][2048] -> WF: B-frag-ordered bf16 planes (R4-proven).
// WF index (ushort/8): ((plane*32 + ktW)*4 + nt)*2 + reg, then lane, then 8 k.
// Lane (fl=lane&15, fg=lane>>4) holds W[nt*16+fl][ktW*64 + reg*32 + fg*8 ..+8].
// Block 0 additionally zeroes the padded accumulators (16384 floats).
__global__ __launch_bounds__(256) void prep_wf(const float* __restrict__ W,
                                               ushort* __restrict__ WF,
                                               float* __restrict__ wsz) {
  const int id = blockIdx.x * 256 + threadIdx.x;  // grid 128 -> 32768
  if (blockIdx.x == 0) {
    const float4 z = {0.f, 0.f, 0.f, 0.f};
    float4* wz4 = (float4*)wsz;
#pragma unroll
    for (int i = 0; i < 16; ++i) wz4[threadIdx.x + (i << 8)] = z;  // 16384 f
  }
  const int lane = id & 63;
  const int reg = (id >> 6) & 1;
  const int nt = (id >> 7) & 3;
  const int kt = (id >> 9) & 31;
  const int plane = id >> 14;  // 0=hi, 1=lo
  const int e = (nt << 4) + (lane & 15);
  const int k0 = (kt << 6) + (reg << 5) + ((lane >> 4) << 3);
  const float* src = W + (size_t)e * HDIM + k0;
  unsigned w[4];
#pragma unroll
  for (int j = 0; j < 4; ++j) {
    float v0 = src[2 * j], v1 = src[2 * j + 1];
    unsigned h0 = bfh(v0), h1 = bfh(v1);
    if (plane) {
      h0 = bfh(v0 - __uint_as_float(h0 << 16));
      h1 = bfh(v1 - __uint_as_float(h1 << 16));
    }
    w[j] = h0 | (h1 << 16);
  }
  *(uint4*)(WF + ((size_t)id << 3)) = make_uint4(w[0], w[1], w[2], w[3]);
}

// ---------------------------------------------------------------------------
// MFMA GEMM in the R9-proven skeleton: grid KS*128; block 512 = 8 waves =
// 4 token-groups(32) x 2 expert-halves(32). Same single-barrier dbuf staging
// cadence; 64-k tiles -> only KR/64 barriers/block. Staging threads convert
// fp32 x -> bf16 hi/lo at write (each element once), slot = g ^ (row&7)
// (R9 XOR family, 2-way banks). B-frags from frag-ordered WF global
// (coalesced 16B/lane, L2-resident). 3-term split per tile:
// acc += al*bh; acc += ah*bl; acc += ah*bh  (R3/R4/R5-passed family),
// k strictly ascending per acc. C/D (m89/R4): row=fg*4+r (tok), col=fl (e).
// Partial store [kh][tok][e]: 16 lanes x 64B contiguous -> coalesced.
template <int KS>
__global__ __launch_bounds__(512, 4) void gate_gemm(
    const float* __restrict__ x,    // [16384][2048]
    const ushort* __restrict__ WF,  // frag-ordered bf16 planes
    float* __restrict__ part) {     // KS x [16384][64], [tok][e]
  constexpr int KR = HDIM / KS;     // k per block
  constexpr int NTILE = KR / 64;    // 64-k tiles
  __shared__ ushort XhL[2][128 * 64];  // 16 KB per buffer
  __shared__ ushort XlL[2][128 * 64];

  const int tid = threadIdx.x;
  const int lane = tid & 63;
  const int wv = __builtin_amdgcn_readfirstlane(tid >> 6);  // 0..7
  const int wtok = (wv & 3) << 5;   // 0,32,64,96
  const int nt0 = (wv >> 2) << 1;   // 0 or 2 (experts [32*(wv>>2), +32))
  const int bid = blockIdx.x;
  const int kh = bid & (KS - 1);
  const int tg = bid >> (KS == 8 ? 3 : 2);
  const int tok0 = tg << 7;         // 128 tokens/block
  const int kb = kh * KR;
  const int kbw = kb >> 6;          // base ktW

  const int fl = lane & 15, fg = lane >> 4;

  // staging map: thread -> row (tid>>2), granule pair (tid&3)*2 (16 floats)
  const int srow = tid >> 2;
  const int sg2 = (tid & 3) << 1;
  const float* xsrc = x + (size_t)(tok0 + srow) * HDIM + kb + (sg2 << 3);
  float fA[16];
  {
    float4 t0 = *(const float4*)xsrc;
    float4 t1 = *(const float4*)(xsrc + 4);
    float4 t2 = *(const float4*)(xsrc + 8);
    float4 t3 = *(const float4*)(xsrc + 12);
    fA[0]=t0.x; fA[1]=t0.y; fA[2]=t0.z; fA[3]=t0.w;
    fA[4]=t1.x; fA[5]=t1.y; fA[6]=t1.z; fA[7]=t1.w;
    fA[8]=t2.x; fA[9]=t2.y; fA[10]=t2.z; fA[11]=t2.w;
    fA[12]=t3.x; fA[13]=t3.y; fA[14]=t3.z; fA[15]=t3.w;
  }
  const int wr0 = srow * 64 + (((sg2 + 0) ^ (srow & 7)) << 3);
  const int wr1 = srow * 64 + (((sg2 + 1) ^ (srow & 7)) << 3);

  f32x4 acc00 = {0.f,0.f,0.f,0.f}, acc01 = {0.f,0.f,0.f,0.f};
  f32x4 acc10 = {0.f,0.f,0.f,0.f}, acc11 = {0.f,0.f,0.f,0.f};

  const int arow0 = wtok + fl;        // m=0 token row
  const int arow1 = wtok + 16 + fl;   // m=1 token row

  for (int kt = 0; kt < NTILE; ++kt) {
    const int buf = kt & 1;
    {  // convert + stage (R9 cadence: write cur, sync, prefetch, compute)
      uint4 h0, l0, h1, l1;
      split8(&fA[0], &h0, &l0);
      split8(&fA[8], &h1, &l1);
      *(uint4*)&XhL[buf][wr0] = h0;
      *(uint4*)&XlL[buf][wr0] = l0;
      *(uint4*)&XhL[buf][wr1] = h1;
      *(uint4*)&XlL[buf][wr1] = l1;
    }
    __syncthreads();  // single barrier/tile (R9-proven dbuf)
    if (kt + 1 < NTILE) {
      const float* xs = xsrc + ((kt + 1) << 6);
      float4 t0 = *(const float4*)xs;
      float4 t1 = *(const float4*)(xs + 4);
      float4 t2 = *(const float4*)(xs + 8);
      float4 t3 = *(const float4*)(xs + 12);
      fA[0]=t0.x; fA[1]=t0.y; fA[2]=t0.z; fA[3]=t0.w;
      fA[4]=t1.x; fA[5]=t1.y; fA[6]=t1.z; fA[7]=t1.w;
      fA[8]=t2.x; fA[9]=t2.y; fA[10]=t2.z; fA[11]=t2.w;
      fA[12]=t3.x; fA[13]=t3.y; fA[14]=t3.z; fA[15]=t3.w;
    }
    const int ktW = kbw + kt;
#pragma unroll
    for (int ss = 0; ss < 2; ++ss) {  // two K32 sub-steps, k ascending
      const int g = (ss << 2) + fg;
      const int ia0 = arow0 * 64 + ((g ^ (arow0 & 7)) << 3);
      const int ia1 = arow1 * 64 + ((g ^ (arow1 & 7)) << 3);
      s16x8 ah0 = *(const s16x8*)&XhL[buf][ia0];
      s16x8 al0 = *(const s16x8*)&XlL[buf][ia0];
      s16x8 ah1 = *(const s16x8*)&XhL[buf][ia1];
      s16x8 al1 = *(const s16x8*)&XlL[buf][ia1];
      const size_t fb0 = ((size_t)(((ktW << 2) + nt0) * 2 + ss) << 9) + (lane << 3);
      const size_t fb1 = ((size_t)(((ktW << 2) + nt0 + 1) * 2 + ss) << 9) + (lane << 3);
      s16x8 bh0 = *(const s16x8*)(WF + fb0);
      s16x8 bl0 = *(const s16x8*)(WF + WFLO + fb0);
      s16x8 bh1 = *(const s16x8*)(WF + fb1);
      s16x8 bl1 = *(const s16x8*)(WF + WFLO + fb1);
      acc00 = __builtin_amdgcn_mfma_f32_16x16x32_bf16(al0, bh0, acc00, 0, 0, 0);
      acc00 = __builtin_amdgcn_mfma_f32_16x16x32_bf16(ah0, bl0, acc00, 0, 0, 0);
      acc00 = __builtin_amdgcn_mfma_f32_16x16x32_bf16(ah0, bh0, acc00, 0, 0, 0);
      acc01 = __builtin_amdgcn_mfma_f32_16x16x32_bf16(al0, bh1, acc01, 0, 0, 0);
      acc01 = __builtin_amdgcn_mfma_f32_16x16x32_bf16(ah0, bl1, acc01, 0, 0, 0);
      acc01 = __builtin_amdgcn_mfma_f32_16x16x32_bf16(ah0, bh1, acc01, 0, 0, 0);
      acc10 = __builtin_amdgcn_mfma_f32_16x16x32_bf16(al1, bh0, acc10, 0, 0, 0);
      acc10 = __builtin_amdgcn_mfma_f32_16x16x32_bf16(ah1, bl0, acc10, 0, 0, 0);
      acc10 = __builtin_amdgcn_mfma_f32_16x16x32_bf16(ah1, bh0, acc10, 0, 0, 0);
      acc11 = __builtin_amdgcn_mfma_f32_16x16x32_bf16(al1, bh1, acc11, 0, 0, 0);
      acc11 = __builtin_amdgcn_mfma_f32_16x16x32_bf16(ah1, bl1, acc11, 0, 0, 0);
      acc11 = __builtin_amdgcn_mfma_f32_16x16x32_bf16(ah1, bh1, acc11, 0, 0, 0);
    }
  }

  // store partials [kh][tok][e]; C/D: tok = wtok + m*16 + fg*4 + r, e = nt*16+fl
  float* pb = part + (size_t)kh * PARTSZ;
  const int e0 = (nt0 << 4) + fl;
#pragma unroll
  for (int r = 0; r < 4; ++r) {
    const int tA = tok0 + wtok + (fg << 2) + r;
    const int tB = tA + 16;
    pb[(size_t)tA * 64 + e0]      = acc00[r];
    pb[(size_t)tA * 64 + e0 + 16] = acc01[r];
    pb[(size_t)tB * 64 + e0]      = acc10[r];
    pb[(size_t)tB * 64 + e0 + 16] = acc11[r];
  }
}

// ---------------------------------------------------------------------------
// Epilogue (R9-proven butterfly top-8); phase 1 re-indexed for [tok][e]
// partial layout (same pairwise tree per (tok,e) -> identical le contents).
#define WRED_SUM(v) { v += __shfl_xor(v, 1);  v += __shfl_xor(v, 2);  \
                      v += __shfl_xor(v, 4);  v += __shfl_xor(v, 8);  \
                      v += __shfl_xor(v, 16); v += __shfl_xor(v, 32); }
#define WRED_MAX(v) { v = fmaxf(v, __shfl_xor(v, 1));  v = fmaxf(v, __shfl_xor(v, 2));  \
                      v = fmaxf(v, __shfl_xor(v, 4));  v = fmaxf(v, __shfl_xor(v, 8));  \
                      v = fmaxf(v, __shfl_xor(v, 16)); v = fmaxf(v, __shfl_xor(v, 32)); }
#define PICK(IJ, WJ) {                                                    \
    float m_ = cand; WRED_MAX(m_);                                        \
    unsigned long long mk_ = __ballot(cand == m_);                        \
    int win_ = (int)__ffsll(mk_) - 1;                                     \
    float bw_ = __shfl(bias_r, win_);                                     \
    WJ = 1.f / (1.f + expf(-(m_ - bw_)));                                 \
    wsum += WJ; IJ = win_;                                                \
    if (lane == win_) { cand = -1e30f; cnt += 1.f; } }

template <int KS>
__global__ __launch_bounds__(512) void gate_epilogue(
    const float* __restrict__ part, const float* __restrict__ bias,
    float* __restrict__ out, float* __restrict__ Pacc,
    float* __restrict__ Cacc) {
  __shared__ float le[64 * 65];      // [token][expert], stride 65
  __shared__ float psum_sh[8][64];
  __shared__ float cnt_sh[8][64];

  const int tid = threadIdx.x;
  const int lane = tid & 63;
  const int wv = tid >> 6;           // 0..7
  const int t0 = blockIdx.x << 6;    // 64 tokens/block

  // phase 1: pairwise-tree sum of KS partials ([tok][e] layout)
  {
    const int tok = tid >> 3;         // 0..63
    const int eo = (tid & 7) << 3;    // 0..56
    const float* p = part + (size_t)(t0 + tok) * 64 + eo;
#pragma unroll
    for (int h = 0; h < 2; ++h) {
      float4 v[KS];
#pragma unroll
      for (int s = 0; s < KS; ++s)
        v[s] = *(const float4*)(p + (size_t)s * PARTSZ + (h << 2));
      float4 r;
      if (KS == 8) {
        r.x = ((v[0].x + v[1].x) + (v[2].x + v[3].x)) + ((v[4].x + v[5].x) + (v[6].x + v[7].x));
        r.y = ((v[0].y + v[1].y) + (v[2].y + v[3].y)) + ((v[4].y + v[5].y) + (v[6].y + v[7].y));
        r.z = ((v[0].z + v[1].z) + (v[2].z + v[3].z)) + ((v[4].z + v[5].z) + (v[6].z + v[7].z));
        r.w = ((v[0].w + v[1].w) + (v[2].w + v[3].w)) + ((v[4].w + v[5].w) + (v[6].w + v[7].w));
      } else {
        r.x = (v[0].x + v[1].x) + (v[2].x + v[3].x);
        r.y = (v[0].y + v[1].y) + (v[2].y + v[3].y);
        r.z = (v[0].z + v[1].z) + (v[2].z + v[3].z);
        r.w = (v[0].w + v[1].w) + (v[2].w + v[3].w);
      }
      const int e = eo + (h << 2);
      le[tok * 65 + e + 0] = r.x; le[tok * 65 + e + 1] = r.y;
      le[tok * 65 + e + 2] = r.z; le[tok * 65 + e + 3] = r.w;
    }
  }
  __syncthreads();

  // phase 2: wave wv handles tokens [8wv, 8wv+8); lane = expert
  const float bias_r = bias[lane];
  float p_acc = 0.f, cnt = 0.f;

  for (int t = (wv << 3); t < (wv << 3) + 8; ++t) {
    float l = le[t * 65 + lane];
    float s = 1.f / (1.f + expf(-l));
    float ss = s;
    WRED_SUM(ss);
    p_acc += s * (1.f / (ss + 1e-10f));

    float cand = l + bias_r;
    float wsum = 0.f;
    int i0, i1, i2, i3, i4, i5, i6, i7;
    float w0, w1, w2, w3, w4, w5, w6, w7;
    PICK(i0, w0); PICK(i1, w1); PICK(i2, w2); PICK(i3, w3);
    PICK(i4, w4); PICK(i5, w5); PICK(i6, w6); PICK(i7, w7);

    if (lane == 0) {
      const float inv = 1.f / (wsum + 1e-10f);
      const int t1 = t0 + t;
      float4 o;
      o.x = (float)i0; o.y = (float)i1; o.z = (float)i2; o.w = (float)i3;
      *(float4*)(out + (size_t)t1 * TOPK) = o;
      o.x = (float)i4; o.y = (float)i5; o.z = (float)i6; o.w = (float)i7;
      *(float4*)(out + (size_t)t1 * TOPK + 4) = o;
      o.x = w0 * inv; o.y = w1 * inv; o.z = w2 * inv; o.w = w3 * inv;
      *(float4*)(out + OFF_W + (size_t)t1 * TOPK) = o;
      o.x = w4 * inv; o.y = w5 * inv; o.z = w6 * inv; o.w = w7 * inv;
      *(float4*)(out + OFF_W + (size_t)t1 * TOPK + 4) = o;
    }
  }

  psum_sh[wv][lane] = p_acc;
  cnt_sh[wv][lane] = cnt;
  __syncthreads();

  // combine 8 wave partials (ascending wv) and emit one atomic per (b,e)
  if (tid < 64) {
    const int b = (int)(blockIdx.x >> 6);  // 64 blocks/batch
    float p = 0.f, c = 0.f;
#pragma unroll
    for (int w = 0; w < 8; ++w) { p += psum_sh[w][tid]; c += cnt_sh[w][tid]; }
    atomicAdd(&Pacc[(size_t)((b << 6) + tid) << 5], p);
    atomicAdd(&Cacc[(size_t)((b << 6) + tid) << 5], c);
  }
}

// ---------------------------------------------------------------------------
// Finalize: 1 block, 1 wave (R8/R9-proven).
__global__ __launch_bounds__(64) void gate_finalize(
    const float* __restrict__ Pacc, const float* __restrict__ Cacc,
    float* __restrict__ out) {
  const int e = threadIdx.x;  // 0..63
  float load = 0.f, partl = 0.f;
#pragma unroll
  for (int bb = 0; bb < NBATCH; ++bb) {
    float c = Cacc[(size_t)((bb << 6) + e) << 5];
    float p = Pacc[(size_t)((bb << 6) + e) << 5];
    load += c;
    partl += (c * (1.f / (TOPK * (float)SLEN))) * (p * (1.f / (float)SLEN));
  }
  out[OFF_LOAD + e] = load;
#pragma unroll
  for (int off = 32; off; off >>= 1) partl += __shfl_down(partl, off);
  if (e == 0) out[OFF_LOSS] = 0.01f * partl * (1.f / (float)NBATCH);
}

// ---------------------------------------------------------------------------
extern "C" void kernel_launch(void* const* d_in, const int* in_sizes, int n_in,
                              void* d_out, int out_size, void* d_ws, size_t ws_size,
                              hipStream_t stream) {
  const float* x = (const float*)d_in[0];     // [4,4096,2048]
  const float* W = (const float*)d_in[1];     // [64,2048]
  const float* bias = (const float*)d_in[2];  // [64]
  float* out = (float*)d_out;

  float* ws = (float*)d_ws;
  float* Pacc = ws + WS_PACC;
  float* Cacc = ws + WS_CACC;
  ushort* WF = (ushort*)(ws + WS_WF);
  float* part = ws + WS_PART;

  prep_wf<<<128, 256, 0, stream>>>(W, WF, ws);

  const size_t need8 = ((size_t)WS_PART + 8 * (size_t)PARTSZ) * sizeof(float);
  if (ws_size >= need8) {
    gate_gemm<8><<<1024, 512, 0, stream>>>(x, WF, part);
    gate_epilogue<8><<<EPI_NBLK, 512, 0, stream>>>(part, bias, out, Pacc, Cacc);
  } else {
    gate_gemm<4><<<512, 512, 0, stream>>>(x, WF, part);
    gate_epilogue<4><<<EPI_NBLK, 512, 0, stream>>>(part, bias, out, Pacc, Cacc);
  }
  gate_finalize<<<1, 64, 0, stream>>>(Pacc, Cacc, out);
}